// Round 4
// baseline (392.444 us; speedup 1.0000x reference)
//
#include <hip/hip_runtime.h>

#define BB 2
#define LL 512
#define DD 64
#define HH 8
#define GG 64
#define KK 4
#define NEGV -1e9f
#define NSLOT 68

#define LD4(arr, r, c_) (*reinterpret_cast<const float4*>(&(arr)[r][c_]))

// ---------------- K1: Q_z = softmax(q_z) over d=64; one wave per row ----------------
__global__ __launch_bounds__(256) void k_softmax_qz(const float* __restrict__ src, float* __restrict__ Qz) {
    int row = blockIdx.x * 4 + (threadIdx.x >> 6);   // B*L = 1024 rows
    int lane = threadIdx.x & 63;
    float v = src[row * DD + lane];
    float m = v;
#pragma unroll
    for (int o = 32; o > 0; o >>= 1) m = fmaxf(m, __shfl_xor(m, o, 64));
    float e = __expf(v - m);
    float s = e;
#pragma unroll
    for (int o = 32; o > 0; o >>= 1) s += __shfl_xor(s, o, 64);
    Qz[row * DD + lane] = e / s;
}

// ---------------- K2: M1/M2 tensor messages ----------------
// M1N[z,k,c,j,a] = sum_b Qz[z,j,b] T[k,a,b,c];  M2N[z,k,c,j,a] = sum_b Qz[z,j,b] T[k,b,a,c]
__global__ __launch_bounds__(256, 3) void k_compute_M(const float* __restrict__ Qz, const float* __restrict__ T,
                            float* __restrict__ M1N, float* __restrict__ M2N) {
    int jt = blockIdx.x;            // 8 j-tiles of 64
    int c  = blockIdx.y;            // 8
    int z  = blockIdx.z >> 2;       // 2
    int k  = blockIdx.z & 3;        // 4
    __shared__ __align__(16) float sQ[64][68];
    __shared__ __align__(16) float sT1[64][68];   // [b][a] = T[k,a,b,c]
    __shared__ __align__(16) float sT2[64][68];   // [b][a] = T[k,b,a,c]
    int tid = threadIdx.x;
#pragma unroll
    for (int idx = tid; idx < 4096; idx += 256) {
        int a = idx >> 6, b = idx & 63;
        sT1[b][a] = T[(((k * 64 + a) * 64 + b) << 3) + c];
        sT2[b][a] = T[(((k * 64 + b) * 64 + a) << 3) + c];
        sQ[a][b]  = Qz[(z * LL + jt * 64 + a) * DD + b];   // a reused as jj here
    }
    __syncthreads();
    int jj = tid >> 2;
    int a0 = (tid & 3) << 4;
    float m1[16], m2[16];
#pragma unroll
    for (int r = 0; r < 16; ++r) { m1[r] = 0.f; m2[r] = 0.f; }
#pragma unroll 4
    for (int b = 0; b < 64; ++b) {
        float q = sQ[jj][b];
#pragma unroll
        for (int u = 0; u < 4; ++u) {
            float4 t1 = LD4(sT1, b, a0 + u * 4);
            float4 t2 = LD4(sT2, b, a0 + u * 4);
            m1[u*4+0] += q * t1.x; m1[u*4+1] += q * t1.y; m1[u*4+2] += q * t1.z; m1[u*4+3] += q * t1.w;
            m2[u*4+0] += q * t2.x; m2[u*4+1] += q * t2.y; m2[u*4+2] += q * t2.z; m2[u*4+3] += q * t2.w;
        }
    }
    int j = jt * 64 + jj;
    size_t base = ((((size_t)z * KK + k) * HH + c) * LL + j) * DD + a0;
#pragma unroll
    for (int u = 0; u < 4; ++u) {
        *reinterpret_cast<float4*>(&M1N[base + u * 4]) =
            make_float4(m1[u*4+0], m1[u*4+1], m1[u*4+2], m1[u*4+3]);
        *reinterpret_cast<float4*>(&M2N[base + u * 4]) =
            make_float4(m2[u*4+0], m2[u*4+1], m2[u*4+2], m2[u*4+3]);
    }
}

// ---------------- K_aux: fused {collapse (512 blk)} {band (2048 blk)} {qg (256 blk)} ----------------
__global__ __launch_bounds__(256) void k_aux(const float* __restrict__ Qz,
        const float* __restrict__ M1N, const float* __restrict__ M2N,
        const float* __restrict__ dp, const float* __restrict__ gp, const int* __restrict__ mask,
        float* __restrict__ MPN, float* __restrict__ MMN,
        float* __restrict__ MP2N, float* __restrict__ MM2N,
        float* __restrict__ BAND, float* __restrict__ QG) {
    int tid = threadIdx.x;
    int b = blockIdx.x;
    if (b < 512) {
        // ---- collapse: MPN = sum_k wt[4][k]*M1N etc. Layout [z,c,j,a] ----
        int idx = b * 256 + tid;
        int a  = (idx & 15) * 4;
        int j  = (idx >> 4) & 511;
        int c  = (idx >> 13) & 7;
        int z  = (idx >> 16) & 1;
        float w4[4], w5[4];
#pragma unroll
        for (int k = 0; k < 4; ++k) { w4[k] = dp[12 + k]; w5[k] = dp[16 + k]; }
        float4 p1 = make_float4(0,0,0,0), m1 = make_float4(0,0,0,0);
        float4 p2 = make_float4(0,0,0,0), m2 = make_float4(0,0,0,0);
#pragma unroll
        for (int k = 0; k < 4; ++k) {
            size_t off = ((((size_t)z * KK + k) * HH + c) * LL + j) * DD + a;
            float4 v1 = *reinterpret_cast<const float4*>(&M1N[off]);
            float4 v2 = *reinterpret_cast<const float4*>(&M2N[off]);
            p1.x += w4[k]*v1.x; p1.y += w4[k]*v1.y; p1.z += w4[k]*v1.z; p1.w += w4[k]*v1.w;
            m1.x += w5[k]*v1.x; m1.y += w5[k]*v1.y; m1.z += w5[k]*v1.z; m1.w += w5[k]*v1.w;
            p2.x += w4[k]*v2.x; p2.y += w4[k]*v2.y; p2.z += w4[k]*v2.z; p2.w += w4[k]*v2.w;
            m2.x += w5[k]*v2.x; m2.y += w5[k]*v2.y; m2.z += w5[k]*v2.z; m2.w += w5[k]*v2.w;
        }
        size_t o = (((size_t)z * HH + c) * LL + j) * DD + a;
        *reinterpret_cast<float4*>(&MPN[o])  = p1;
        *reinterpret_cast<float4*>(&MMN[o])  = m1;
        *reinterpret_cast<float4*>(&MP2N[o]) = p2;
        *reinterpret_cast<float4*>(&MM2N[o]) = m2;
    } else if (b < 2560) {
        // ---- band: BAND[z,c,j,d+3] = sum_a Qz[j+d,a] * (sum_k wt[tdx(d)][k]*M1N[k,c,j,a]) ----
        int w = (b - 512) * 4 + (tid >> 6);
        int lane = tid & 63;
        int j = w & 511, c = (w >> 9) & 7, z = w >> 12;
        float m[4];
#pragma unroll
        for (int k = 0; k < 4; ++k)
            m[k] = M1N[((((size_t)z * KK + k) * HH + c) * LL + j) * DD + lane];
        float out = 0.f;
#pragma unroll
        for (int d = -3; d <= 3; ++d) {
            int i = j + d;
            if (i < 0 || i >= LL) continue;
            int idx = d < 0 ? d + 9 : d;
            float t = 0.f;
            if (idx != 0) {
#pragma unroll
                for (int k = 0; k < 4; ++k) t += dp[(idx - 1) * 4 + k] * m[k];
            }
            float s = Qz[(z * LL + i) * DD + lane] * t;
#pragma unroll
            for (int o = 32; o > 0; o >>= 1) s += __shfl_xor(s, o, 64);
            if (lane == d + 3) out = s;
        }
        if (lane < 7) BAND[(size_t)w * 8 + lane] = out;
    } else {
        // ---- qg: Q_g = softmax_g( Qz . gp^T ) ----
        __shared__ __align__(16) float gpS[64][68];
#pragma unroll
        for (int idx = tid; idx < 4096; idx += 256) gpS[idx >> 6][idx & 63] = gp[idx];
        __syncthreads();
        int row = (b - 2560) * 4 + (tid >> 6);
        int g = tid & 63;
        float qv = Qz[row * DD + g];
        float s = 0.f;
#pragma unroll 8
        for (int a = 0; a < 64; ++a) s += __shfl(qv, a, 64) * gpS[g][a];
        if (mask[row] == 0) s = NEGV;
        float m = s;
#pragma unroll
        for (int o = 32; o > 0; o >>= 1) m = fmaxf(m, __shfl_xor(m, o, 64));
        float e = __expf(s - m);
        float sum = e;
#pragma unroll
        for (int o = 32; o > 0; o >>= 1) sum += __shfl_xor(sum, o, 64);
        QG[row * GG + g] = e / sum;
    }
}

#define GEMM_ACC(ACC) \
        _Pragma("unroll 4") \
        for (int a4 = 0; a4 < 64; a4 += 4) { \
            float bvv[4][4]; \
            _Pragma("unroll") \
            for (int u = 0; u < 4; ++u) { \
                float4 b4 = LD4(sB, a4 + u, tx * 4); \
                bvv[u][0] = b4.x; bvv[u][1] = b4.y; bvv[u][2] = b4.z; bvv[u][3] = b4.w; } \
            _Pragma("unroll") \
            for (int q = 0; q < 4; ++q) { \
                float4 a4v = LD4(sA, ty * 4 + q, a4); \
                _Pragma("unroll") \
                for (int r = 0; r < 4; ++r) \
                    ACC[q][r] += a4v.x * bvv[0][r] + a4v.y * bvv[1][r] \
                               + a4v.z * bvv[2][r] + a4v.w * bvv[3][r]; } \
        }

// ---------------- K3a: s_h main GEMM + band overwrite + mask ----------------
__global__ __launch_bounds__(256, 4) void k_sh(const float* __restrict__ Qz,
                     const float* __restrict__ MPN, const float* __restrict__ MMN,
                     const float* __restrict__ BAND, const int* __restrict__ mask,
                     float* __restrict__ SH) {
    int jt = blockIdx.x, it = blockIdx.y;
    int z = blockIdx.z >> 3, c = blockIdx.z & 7;
    __shared__ __align__(16) float sA[64][68];   // [ii][a]
    __shared__ __align__(16) float sB[64][68];   // [a][jj]  (transposed on load)
    int tid = threadIdx.x;
#pragma unroll
    for (int idx = tid; idx < 4096; idx += 256) {
        int ii = idx >> 6, a = idx & 63;
        sA[ii][a] = Qz[(z * LL + it * 64 + ii) * DD + a];
    }
    int ty = tid >> 4, tx = tid & 15;
    bool diag = (it == jt);
    int npass = diag ? 2 : 1;
    float accP[4][4] = {};
    float accM[4][4] = {};
    for (int pass = 0; pass < npass; ++pass) {
        const float* Bmat = (pass == 0) ? (diag ? MPN : (it > jt ? MPN : MMN)) : MMN;
        __syncthreads();
#pragma unroll
        for (int idx = tid; idx < 4096; idx += 256) {
            int jj = idx >> 6, a = idx & 63;
            sB[a][jj] = Bmat[(((size_t)z * HH + c) * LL + jt * 64 + jj) * DD + a];
        }
        __syncthreads();
        if (pass == 0) { GEMM_ACC(accP) } else { GEMM_ACC(accM) }
    }
    int mi[4], mj[4];
#pragma unroll
    for (int q = 0; q < 4; ++q) {
        mi[q] = mask[z * LL + it * 64 + ty * 4 + q];
        mj[q] = mask[z * LL + jt * 64 + tx * 4 + q];
    }
#pragma unroll
    for (int q = 0; q < 4; ++q) {
        int i = it * 64 + ty * 4 + q;
        float vals[4];
#pragma unroll
        for (int r = 0; r < 4; ++r) {
            int j = jt * 64 + tx * 4 + r;
            float v = (diag && i <= j) ? accM[q][r] : accP[q][r];
            int d = i - j;
            if (d >= -3 && d <= 3)
                v = BAND[(((size_t)(z * HH + c) * LL + j)) * 8 + (d + 3)];
            vals[r] = (mi[q] && mj[r]) ? v : NEGV;
        }
        *reinterpret_cast<float4*>(&SH[(((size_t)z * HH + c) * LL + i) * LL + jt * 64 + tx * 4]) =
            make_float4(vals[0], vals[1], vals[2], vals[3]);
    }
}

// ---------------- K3b: Q_h = softmax over j (512); one wave per row, in place ----------------
__global__ __launch_bounds__(256) void k_softmax_sh(float* __restrict__ SH) {
    int row = blockIdx.x * 4 + (threadIdx.x >> 6);   // B*H*L = 8192 rows
    int lane = threadIdx.x & 63;
    float v[8];
    float m = -1e30f;
#pragma unroll
    for (int r = 0; r < 8; ++r) { v[r] = SH[(size_t)row * LL + r * 64 + lane]; m = fmaxf(m, v[r]); }
#pragma unroll
    for (int o = 32; o > 0; o >>= 1) m = fmaxf(m, __shfl_xor(m, o, 64));
    float s = 0.f;
#pragma unroll
    for (int r = 0; r < 8; ++r) { v[r] = __expf(v[r] - m); s += v[r]; }
#pragma unroll
    for (int o = 32; o > 0; o >>= 1) s += __shfl_xor(s, o, 64);
    float inv = 1.f / s;
#pragma unroll
    for (int r = 0; r < 8; ++r) SH[(size_t)row * LL + r * 64 + lane] = v[r] * inv;
}

// ---------------- K_g12: fused g1 (which=0) / g2 (which=1) main GEMMs ----------------
// g1[i,a] = sum_{c,j} Qh[c,i,j] * Mmain1[c,j,a];  g2[i,a] = sum_{c,j} Qh[c,j,i] * Mmain2[c,j,a]
__global__ __launch_bounds__(256, 4) void k_g12(const float* __restrict__ SH,
                     const float* __restrict__ MPN, const float* __restrict__ MMN,
                     const float* __restrict__ MP2N, const float* __restrict__ MM2N,
                     float* __restrict__ PG) {
    int it = blockIdx.x, jc = blockIdx.y;
    int which = blockIdx.z >> 4;
    int z = (blockIdx.z >> 3) & 1, c = blockIdx.z & 7;
    const float* BP = which ? MP2N : MPN;
    const float* BM = which ? MM2N : MMN;
    __shared__ __align__(16) float sQh[64][68];
    __shared__ __align__(16) float sB[64][68];    // [jj][a]
    int tid = threadIdx.x;
    int ty = tid >> 4, tx = tid & 15;
    int ibase = it * 64 + ty * 4;
    float acc[4][4] = {};
    for (int js = 0; js < 2; ++js) {
        int j0 = jc * 128 + js * 64;
        __syncthreads();
        if (which == 0) {
            // sQh[ii][jj] = Qh[c, i, j]
#pragma unroll
            for (int idx = tid; idx < 4096; idx += 256) {
                int ii = idx >> 6, jjl = idx & 63;
                sQh[ii][jjl] = SH[(((size_t)z * HH + c) * LL + it * 64 + ii) * LL + j0 + jjl];
            }
        } else {
            // sQh[jj][ii] = Qh[c, j, i]
#pragma unroll
            for (int idx = tid; idx < 4096; idx += 256) {
                int jjl = idx >> 6, ii = idx & 63;
                sQh[jjl][ii] = SH[(((size_t)z * HH + c) * LL + j0 + jjl) * LL + it * 64 + ii];
            }
        }
        bool dg = (j0 == it * 64);
        int npass = dg ? 2 : 1;
        for (int pass = 0; pass < npass; ++pass) {
            bool useP = dg ? (pass == 0) : (which == 0 ? (j0 < it * 64) : (j0 > it * 64));
            const float* Bmat = useP ? BP : BM;
            __syncthreads();
#pragma unroll
            for (int idx = tid; idx < 4096; idx += 256) {
                int jjl = idx >> 6, a = idx & 63;
                sB[jjl][a] = Bmat[(((size_t)z * HH + c) * LL + j0 + jjl) * DD + a];
            }
            __syncthreads();
            if (!dg) {
                if (which == 0) {
#pragma unroll 8
                    for (int jj = 0; jj < 64; ++jj) {
                        float4 b4 = LD4(sB, jj, tx * 4);
#pragma unroll
                        for (int q = 0; q < 4; ++q) {
                            float w = sQh[ty * 4 + q][jj];
                            acc[q][0] += w * b4.x; acc[q][1] += w * b4.y;
                            acc[q][2] += w * b4.z; acc[q][3] += w * b4.w;
                        }
                    }
                } else {
#pragma unroll 8
                    for (int jj = 0; jj < 64; ++jj) {
                        float4 b4 = LD4(sB, jj, tx * 4);
#pragma unroll
                        for (int q = 0; q < 4; ++q) {
                            float w = sQh[jj][ty * 4 + q];
                            acc[q][0] += w * b4.x; acc[q][1] += w * b4.y;
                            acc[q][2] += w * b4.z; acc[q][3] += w * b4.w;
                        }
                    }
                }
            } else {
                // diagonal block: select by triangle
#pragma unroll 4
                for (int jj = 0; jj < 64; ++jj) {
                    int j = j0 + jj;
                    float4 b4 = LD4(sB, jj, tx * 4);
#pragma unroll
                    for (int q = 0; q < 4; ++q) {
                        int i = ibase + q;
                        float qh = which == 0 ? sQh[ty * 4 + q][jj] : sQh[jj][ty * 4 + q];
                        bool gt = which == 0 ? (i > j) : (j > i);
                        float w = ((pass == 0) == gt) ? qh : 0.f;
                        acc[q][0] += w * b4.x; acc[q][1] += w * b4.y;
                        acc[q][2] += w * b4.z; acc[q][3] += w * b4.w;
                    }
                }
            }
        }
    }
    int slot = which * 32 + c * 4 + jc;
#pragma unroll
    for (int q = 0; q < 4; ++q)
        *reinterpret_cast<float4*>(&PG[(((size_t)slot * BB + z) * LL + ibase + q) * DD + tx * 4]) =
            make_float4(acc[q][0], acc[q][1], acc[q][2], acc[q][3]);
}

// ---------------- K_corr12: band corrections for g1 (blocks<512) and g2 ----------------
__global__ __launch_bounds__(256) void k_corr12(const float* __restrict__ SH,
                      const float* __restrict__ M1N, const float* __restrict__ M2N,
                      const float* __restrict__ MPN, const float* __restrict__ MMN,
                      const float* __restrict__ MP2N, const float* __restrict__ MM2N,
                      const float* __restrict__ dp, float* __restrict__ PG) {
    int bid = blockIdx.x;
    int which = bid >> 9; bid &= 511;
    int w = bid * 4 + (threadIdx.x >> 6);          // 2048 waves per half: (z,i,chalf)
    int lane = threadIdx.x & 63;
    int ch = w & 1, i = (w >> 1) & 511, z = w >> 10;
    const float* Mx = which ? M2N : M1N;
    const float* MP = which ? MP2N : MPN;
    const float* MM = which ? MM2N : MMN;
    float acc = 0.f;
    for (int cc = 0; cc < 4; ++cc) {
        int c = ch * 4 + cc;
#pragma unroll
        for (int d = -3; d <= 3; ++d) {
            int j = which ? i + d : i - d;         // d = i-j (g1) or j-i (g2)
            if (j < 0 || j >= LL) continue;
            float qh = which ? SH[(((size_t)z * HH + c) * LL + j) * LL + i]
                             : SH[(((size_t)z * HH + c) * LL + i) * LL + j];
            int idx = d < 0 ? d + 9 : d;
            float e = 0.f;
            if (idx != 0) {
#pragma unroll
                for (int k = 0; k < 4; ++k)
                    e += dp[(idx - 1) * 4 + k] *
                         Mx[((((size_t)z * KK + k) * HH + c) * LL + j) * DD + lane];
            }
            const float* mainM = (d > 0) ? MP : MM;
            float mn = mainM[(((size_t)z * HH + c) * LL + j) * DD + lane];
            acc += qh * (e - mn);
        }
    }
    int slot = 64 + which * 2 + ch;
    PG[(((size_t)slot * BB + z) * LL + i) * DD + lane] = acc;
}

// ---------------- K7: q_next = x + sum(NSLOT partial slots) + gg ----------------
__global__ __launch_bounds__(256) void k_update(const float* __restrict__ x, const float* __restrict__ PG,
                         const float* __restrict__ QG, const float* __restrict__ gp,
                         float* __restrict__ outq) {
    __shared__ __align__(16) float gpS[64][68];   // [g][a]
    int tid = threadIdx.x;
#pragma unroll
    for (int idx = tid; idx < 4096; idx += 256) gpS[idx >> 6][idx & 63] = gp[idx];
    __syncthreads();
    int row = blockIdx.x * 4 + (tid >> 6);        // B*L
    int a = tid & 63;
    float acc = x[row * DD + a];
    float qgv = QG[row * GG + a];
#pragma unroll 8
    for (int g = 0; g < 64; ++g) acc += __shfl(qgv, g, 64) * gpS[g][a];
#pragma unroll 8
    for (int s = 0; s < NSLOT; ++s) acc += PG[((size_t)s * BB * LL + row) * DD + a];
    outq[row * DD + a] = acc;
}

extern "C" void kernel_launch(void* const* d_in, const int* in_sizes, int n_in,
                              void* d_out, int out_size, void* d_ws, size_t ws_size,
                              hipStream_t stream) {
    const float* x    = (const float*)d_in[0];
    const int*   mask = (const int*)d_in[1];
    const float* dp   = (const float*)d_in[2];
    const float* T    = (const float*)d_in[3];
    const float* gp   = (const float*)d_in[4];
    float* out = (float*)d_out;
    float* ws  = (float*)d_ws;

    const size_t nQZ = (size_t)BB * LL * DD;            // 65536
    const size_t nM  = (size_t)BB * KK * HH * LL * DD;  // 2097152
    const size_t nC  = (size_t)BB * HH * LL * DD;       // 524288
    const size_t nBD = (size_t)BB * HH * LL * 8;        // 65536
    const size_t nSH = (size_t)BB * HH * LL * LL;       // 4194304
    const size_t nQG = (size_t)BB * LL * GG;            // 65536
    const size_t nPG = (size_t)NSLOT * BB * LL * DD;    // 4456448

    float* Qz   = ws;
    float* M1N  = Qz + nQZ;
    float* M2N  = M1N + nM;
    float* MPN  = M2N + nM;
    float* MMN  = MPN + nC;
    float* MP2N = MMN + nC;
    float* MM2N = MP2N + nC;
    float* BAND = MM2N + nC;
    float* SH   = BAND + nBD;
    float* QG   = SH + nSH;
    float* PG   = QG + nQG;
    float* QZ1  = PG + nPG;
    // total ws use: ~61 MB

    const float* qsrc = x;
    for (int iter = 0; iter < 2; ++iter) {
        float* qdst = (iter == 0) ? QZ1 : out;
        hipLaunchKernelGGL(k_softmax_qz, dim3(256), dim3(256), 0, stream, qsrc, Qz);
        hipLaunchKernelGGL(k_compute_M, dim3(8, 8, 8), dim3(256), 0, stream, Qz, T, M1N, M2N);
        hipLaunchKernelGGL(k_aux, dim3(2816), dim3(256), 0, stream, Qz, M1N, M2N, dp, gp, mask,
                           MPN, MMN, MP2N, MM2N, BAND, QG);
        hipLaunchKernelGGL(k_sh, dim3(8, 8, 16), dim3(256), 0, stream, Qz, MPN, MMN, BAND, mask, SH);
        hipLaunchKernelGGL(k_softmax_sh, dim3(2048), dim3(256), 0, stream, SH);
        hipLaunchKernelGGL(k_g12, dim3(8, 4, 32), dim3(256), 0, stream, SH, MPN, MMN, MP2N, MM2N, PG);
        hipLaunchKernelGGL(k_corr12, dim3(1024), dim3(256), 0, stream, SH, M1N, M2N,
                           MPN, MMN, MP2N, MM2N, dp, PG);
        hipLaunchKernelGGL(k_update, dim3(256), dim3(256), 0, stream, x, PG, QG, gp, qdst);
        qsrc = qdst;
    }
}

// Round 6
// 195.119 us; speedup vs baseline: 2.0113x; 2.0113x over previous
//
#include <hip/hip_runtime.h>

#define BB 2
#define LL 512
#define DD 64
#define HH 8
#define GG 64
#define KK 4
#define NEGV -1e9f
#define NSLOT 36

typedef unsigned short ushort_t;
typedef __attribute__((ext_vector_type(8))) short bf16x8;
typedef __attribute__((ext_vector_type(4))) float f32x4;
#define MFMA(a, b, c) __builtin_amdgcn_mfma_f32_16x16x32_bf16(a, b, c, 0, 0, 0)

__device__ __forceinline__ ushort_t f2b(float f) {
    unsigned int u = __float_as_uint(f);
    return (ushort_t)((u + 0x7FFFu + ((u >> 16) & 1u)) >> 16);
}
__device__ __forceinline__ float b2f(ushort_t s) {
    return __uint_as_float(((unsigned int)s) << 16);
}

// stage a 64x64 bf16 tile (row-major, rowstride elems) into LDS with granule-XOR swizzle
__device__ __forceinline__ void stage64(ushort_t* dst, const ushort_t* src,
                                        int rowstride, int tid) {
#pragma unroll
    for (int g = tid; g < 512; g += 256) {
        int row = g >> 3, colg = g & 7;
        uint4 v = *reinterpret_cast<const uint4*>(&src[row * rowstride + (colg << 3)]);
        *reinterpret_cast<uint4*>(&dst[(row << 6) + ((colg ^ (row & 7)) << 3)]) = v;
    }
}
// read an 8-elem fragment (col multiple of 8) from swizzled LDS tile
__device__ __forceinline__ bf16x8 frag(const ushort_t* s, int row, int col) {
    return *reinterpret_cast<const bf16x8*>(&s[(row << 6) + ((((col >> 3) ^ (row & 7))) << 3)]);
}
__device__ __forceinline__ bf16x8 maskfrag(bf16x8 v, int cnt, bool keep_prefix) {
    bf16x8 r;
#pragma unroll
    for (int u = 0; u < 8; ++u) {
        bool keep = keep_prefix ? (u < cnt) : (u >= cnt);
        r[u] = keep ? v[u] : (short)0;
    }
    return r;
}
__device__ __forceinline__ int iclamp(int v, int lo, int hi) {
    return v < lo ? lo : (v > hi ? hi : v);
}

// ---------------- K1: Q_z = softmax(q_z) over d=64; fp32 + bf16 outputs ----------------
__global__ __launch_bounds__(256) void k_softmax_qz(const float* __restrict__ src,
                                                    float* __restrict__ Qz,
                                                    ushort_t* __restrict__ QzB) {
    int row = blockIdx.x * 4 + (threadIdx.x >> 6);
    int lane = threadIdx.x & 63;
    float v = src[row * DD + lane];
    float m = v;
#pragma unroll
    for (int o = 32; o > 0; o >>= 1) m = fmaxf(m, __shfl_xor(m, o, 64));
    float e = __expf(v - m);
    float s = e;
#pragma unroll
    for (int o = 32; o > 0; o >>= 1) s += __shfl_xor(s, o, 64);
    float r = e / s;
    Qz[row * DD + lane] = r;
    QzB[row * DD + lane] = f2b(r);
}

// ---------------- K2: M1/M2 tensor messages (fp32 accum, bf16 store) ----------------
#define LD4S(arr, r, c_) (*reinterpret_cast<const float4*>(&(arr)[r][c_]))
__global__ __launch_bounds__(256, 3) void k_compute_M(const float* __restrict__ Qz, const float* __restrict__ T,
                            ushort_t* __restrict__ M1Nb, ushort_t* __restrict__ M2Nb) {
    int jt = blockIdx.x;
    int c  = blockIdx.y;
    int z  = blockIdx.z >> 2;
    int k  = blockIdx.z & 3;
    __shared__ __align__(16) float sQ[64][68];
    __shared__ __align__(16) float sT1[64][68];
    __shared__ __align__(16) float sT2[64][68];
    int tid = threadIdx.x;
#pragma unroll
    for (int idx = tid; idx < 4096; idx += 256) {
        int a = idx >> 6, b = idx & 63;
        sT1[b][a] = T[(((k * 64 + a) * 64 + b) << 3) + c];
        sT2[b][a] = T[(((k * 64 + b) * 64 + a) << 3) + c];
        sQ[a][b]  = Qz[(z * LL + jt * 64 + a) * DD + b];
    }
    __syncthreads();
    int jj = tid >> 2;
    int a0 = (tid & 3) << 4;
    float m1[16], m2[16];
#pragma unroll
    for (int r = 0; r < 16; ++r) { m1[r] = 0.f; m2[r] = 0.f; }
#pragma unroll 4
    for (int b = 0; b < 64; ++b) {
        float q = sQ[jj][b];
#pragma unroll
        for (int u = 0; u < 4; ++u) {
            float4 t1 = LD4S(sT1, b, a0 + u * 4);
            float4 t2 = LD4S(sT2, b, a0 + u * 4);
            m1[u*4+0] += q * t1.x; m1[u*4+1] += q * t1.y; m1[u*4+2] += q * t1.z; m1[u*4+3] += q * t1.w;
            m2[u*4+0] += q * t2.x; m2[u*4+1] += q * t2.y; m2[u*4+2] += q * t2.z; m2[u*4+3] += q * t2.w;
        }
    }
    int j = jt * 64 + jj;
    ushort_t o1[16], o2[16];
#pragma unroll
    for (int r = 0; r < 16; ++r) { o1[r] = f2b(m1[r]); o2[r] = f2b(m2[r]); }
    size_t base = ((((size_t)z * KK + k) * HH + c) * LL + j) * DD + a0;
    *reinterpret_cast<uint4*>(&M1Nb[base])     = *reinterpret_cast<uint4*>(&o1[0]);
    *reinterpret_cast<uint4*>(&M1Nb[base + 8]) = *reinterpret_cast<uint4*>(&o1[8]);
    *reinterpret_cast<uint4*>(&M2Nb[base])     = *reinterpret_cast<uint4*>(&o2[0]);
    *reinterpret_cast<uint4*>(&M2Nb[base + 8]) = *reinterpret_cast<uint4*>(&o2[8]);
}

// ---------------- K2b: collapse -> bf16 natural [j][a] + transposed [a][j] layouts ----------------
__global__ __launch_bounds__(256, 2) void k_collapse(const ushort_t* __restrict__ M1Nb,
        const ushort_t* __restrict__ M2Nb, const float* __restrict__ dp,
        ushort_t* __restrict__ MPNb, ushort_t* __restrict__ MMNb,
        ushort_t* __restrict__ MP2Nb, ushort_t* __restrict__ MM2Nb,
        ushort_t* __restrict__ MPT, ushort_t* __restrict__ MMT,
        ushort_t* __restrict__ MP2T, ushort_t* __restrict__ MM2T) {
    int jt = blockIdx.x;            // 8
    int zc = blockIdx.y;            // 16 = z*8+c
    int z = zc >> 3, c = zc & 7;
    __shared__ float sP1[64 * 65], sM1[64 * 65], sP2[64 * 65], sM2[64 * 65];
    int tid = threadIdx.x;
    float w4[4], w5[4];
#pragma unroll
    for (int k = 0; k < 4; ++k) { w4[k] = dp[12 + k]; w5[k] = dp[16 + k]; }
    size_t b0 = (((size_t)z * KK * HH + c) * LL + jt * 64) * DD;
    const size_t kstr = (size_t)HH * LL * DD;
    for (int g = tid; g < 512; g += 256) {
        int j = g >> 3, a0 = (g & 7) * 8;
        size_t o = b0 + (size_t)j * DD + a0;
        float p1[8] = {}, q1[8] = {}, p2[8] = {}, q2[8] = {};
#pragma unroll
        for (int k = 0; k < 4; ++k) {
            uint4 v1 = *reinterpret_cast<const uint4*>(&M1Nb[o + k * kstr]);
            uint4 v2 = *reinterpret_cast<const uint4*>(&M2Nb[o + k * kstr]);
            const ushort_t* s1 = reinterpret_cast<const ushort_t*>(&v1);
            const ushort_t* s2 = reinterpret_cast<const ushort_t*>(&v2);
#pragma unroll
            for (int u = 0; u < 8; ++u) {
                float f1 = b2f(s1[u]), f2v = b2f(s2[u]);
                p1[u] += w4[k] * f1; q1[u] += w5[k] * f1;
                p2[u] += w4[k] * f2v; q2[u] += w5[k] * f2v;
            }
        }
        ushort_t t1[8], t2[8], t3[8], t4[8];
#pragma unroll
        for (int u = 0; u < 8; ++u) {
            t1[u] = f2b(p1[u]); t2[u] = f2b(q1[u]); t3[u] = f2b(p2[u]); t4[u] = f2b(q2[u]);
            sP1[(a0 + u) * 65 + j] = p1[u]; sM1[(a0 + u) * 65 + j] = q1[u];
            sP2[(a0 + u) * 65 + j] = p2[u]; sM2[(a0 + u) * 65 + j] = q2[u];
        }
        size_t on = ((size_t)zc * LL + jt * 64 + j) * DD + a0;
        *reinterpret_cast<uint4*>(&MPNb[on])  = *reinterpret_cast<uint4*>(t1);
        *reinterpret_cast<uint4*>(&MMNb[on])  = *reinterpret_cast<uint4*>(t2);
        *reinterpret_cast<uint4*>(&MP2Nb[on]) = *reinterpret_cast<uint4*>(t3);
        *reinterpret_cast<uint4*>(&MM2Nb[on]) = *reinterpret_cast<uint4*>(t4);
    }
    __syncthreads();
    for (int g = tid; g < 512; g += 256) {
        int a = g >> 3, j0g = (g & 7) * 8;
        ushort_t t1[8], t2[8], t3[8], t4[8];
#pragma unroll
        for (int u = 0; u < 8; ++u) {
            t1[u] = f2b(sP1[a * 65 + j0g + u]); t2[u] = f2b(sM1[a * 65 + j0g + u]);
            t3[u] = f2b(sP2[a * 65 + j0g + u]); t4[u] = f2b(sM2[a * 65 + j0g + u]);
        }
        size_t ot = ((size_t)zc * DD + a) * LL + jt * 64 + j0g;
        *reinterpret_cast<uint4*>(&MPT[ot])  = *reinterpret_cast<uint4*>(t1);
        *reinterpret_cast<uint4*>(&MMT[ot])  = *reinterpret_cast<uint4*>(t2);
        *reinterpret_cast<uint4*>(&MP2T[ot]) = *reinterpret_cast<uint4*>(t3);
        *reinterpret_cast<uint4*>(&MM2T[ot]) = *reinterpret_cast<uint4*>(t4);
    }
}

// ---------------- K2c: fused {band (2048 blk)} {qg (256 blk)} ----------------
__global__ __launch_bounds__(256) void k_aux2(const float* __restrict__ Qz,
        const ushort_t* __restrict__ M1Nb, const float* __restrict__ dp,
        const float* __restrict__ gp, const int* __restrict__ mask,
        float* __restrict__ BAND, float* __restrict__ QG) {
    int tid = threadIdx.x;
    int b = blockIdx.x;
    if (b < 2048) {
        int w = b * 4 + (tid >> 6);
        int lane = tid & 63;
        int j = w & 511, c = (w >> 9) & 7, z = w >> 12;
        float m[4];
#pragma unroll
        for (int k = 0; k < 4; ++k)
            m[k] = b2f(M1Nb[((((size_t)z * KK + k) * HH + c) * LL + j) * DD + lane]);
        float out = 0.f;
#pragma unroll
        for (int d = -3; d <= 3; ++d) {
            int i = j + d;
            if (i < 0 || i >= LL) continue;
            int idx = d < 0 ? d + 9 : d;
            float t = 0.f;
            if (idx != 0) {
#pragma unroll
                for (int k = 0; k < 4; ++k) t += dp[(idx - 1) * 4 + k] * m[k];
            }
            float s = Qz[(z * LL + i) * DD + lane] * t;
#pragma unroll
            for (int o = 32; o > 0; o >>= 1) s += __shfl_xor(s, o, 64);
            if (lane == d + 3) out = s;
        }
        if (lane < 7) BAND[(size_t)w * 8 + lane] = out;
    } else {
        __shared__ __align__(16) float gpS[64][68];
#pragma unroll
        for (int idx = tid; idx < 4096; idx += 256) gpS[idx >> 6][idx & 63] = gp[idx];
        __syncthreads();
        int row = (b - 2048) * 4 + (tid >> 6);
        int g = tid & 63;
        float qv = Qz[row * DD + g];
        float s = 0.f;
#pragma unroll 8
        for (int a = 0; a < 64; ++a) s += __shfl(qv, a, 64) * gpS[g][a];
        if (mask[row] == 0) s = NEGV;
        float m = s;
#pragma unroll
        for (int o = 32; o > 0; o >>= 1) m = fmaxf(m, __shfl_xor(m, o, 64));
        float e = __expf(s - m);
        float sum = e;
#pragma unroll
        for (int o = 32; o > 0; o >>= 1) sum += __shfl_xor(sum, o, 64);
        QG[row * GG + g] = e / sum;
    }
}

// ---------------- K3a: s_h via MFMA + band overwrite + mask ----------------
__global__ __launch_bounds__(256, 4) void k_sh(const ushort_t* __restrict__ QzB,
        const ushort_t* __restrict__ MPNb, const ushort_t* __restrict__ MMNb,
        const float* __restrict__ BAND, const int* __restrict__ mask,
        float* __restrict__ SH) {
    int jt = blockIdx.x, it = blockIdx.y;
    int z = blockIdx.z >> 3, c = blockIdx.z & 7;
    __shared__ ushort_t sA[4096], sB[4096];
    int tid = threadIdx.x;
    stage64(sA, QzB + ((size_t)(z * LL + it * 64)) * DD, DD, tid);
    bool diag = (it == jt);
    size_t bbase = ((size_t)(z * HH + c) * LL + jt * 64) * DD;
    const ushort_t* B0 = diag ? MPNb : (it > jt ? MPNb : MMNb);
    stage64(sB, B0 + bbase, DD, tid);
    __syncthreads();
    int w = tid >> 6, lm = tid & 15, lg = (tid & 63) >> 4;
    f32x4 accP[4], accM[4];
#pragma unroll
    for (int nf = 0; nf < 4; ++nf) { accP[nf] = {0.f,0.f,0.f,0.f}; accM[nf] = {0.f,0.f,0.f,0.f}; }
#pragma unroll
    for (int ks = 0; ks < 2; ++ks) {
        int kc = ks * 32 + lg * 8;
        bf16x8 af = frag(sA, w * 16 + lm, kc);
#pragma unroll
        for (int nf = 0; nf < 4; ++nf)
            accP[nf] = MFMA(af, frag(sB, nf * 16 + lm, kc), accP[nf]);
    }
    if (diag) {
        __syncthreads();
        stage64(sB, MMNb + bbase, DD, tid);
        __syncthreads();
#pragma unroll
        for (int ks = 0; ks < 2; ++ks) {
            int kc = ks * 32 + lg * 8;
            bf16x8 af = frag(sA, w * 16 + lm, kc);
#pragma unroll
            for (int nf = 0; nf < 4; ++nf)
                accM[nf] = MFMA(af, frag(sB, nf * 16 + lm, kc), accM[nf]);
        }
    }
    int mi[4];
#pragma unroll
    for (int r = 0; r < 4; ++r) mi[r] = mask[z * LL + it * 64 + w * 16 + lg * 4 + r];
#pragma unroll
    for (int nf = 0; nf < 4; ++nf) {
        int j = jt * 64 + nf * 16 + lm;
        int mjv = mask[z * LL + j];
#pragma unroll
        for (int r = 0; r < 4; ++r) {
            int i = it * 64 + w * 16 + lg * 4 + r;
            float v = (diag && i <= j) ? accM[nf][r] : accP[nf][r];
            int d = i - j;
            if (d >= -3 && d <= 3)
                v = BAND[((size_t)((z * HH + c) * LL + j)) * 8 + (d + 3)];
            if (!(mi[r] && mjv)) v = NEGV;
            SH[((size_t)(z * HH + c) * LL + i) * LL + j] = v;
        }
    }
}

// ---------------- K3b: Q_h softmax over j; fp32 in-place + bf16 copy ----------------
__global__ __launch_bounds__(256) void k_softmax_sh(float* __restrict__ SH,
                                                    ushort_t* __restrict__ SHB) {
    int row = blockIdx.x * 4 + (threadIdx.x >> 6);
    int lane = threadIdx.x & 63;
    float v[8];
    float m = -1e30f;
#pragma unroll
    for (int r = 0; r < 8; ++r) { v[r] = SH[(size_t)row * LL + r * 64 + lane]; m = fmaxf(m, v[r]); }
#pragma unroll
    for (int o = 32; o > 0; o >>= 1) m = fmaxf(m, __shfl_xor(m, o, 64));
    float s = 0.f;
#pragma unroll
    for (int r = 0; r < 8; ++r) { v[r] = __expf(v[r] - m); s += v[r]; }
#pragma unroll
    for (int o = 32; o > 0; o >>= 1) s += __shfl_xor(s, o, 64);
    float inv = 1.f / s;
#pragma unroll
    for (int r = 0; r < 8; ++r) {
        float nv = v[r] * inv;
        SH[(size_t)row * LL + r * 64 + lane] = nv;
        SHB[(size_t)row * LL + r * 64 + lane] = f2b(nv);
    }
}

// ---------------- K3c: SHBT[zc][i][j] = SHB-content[zc][j][i]  (64x64 LDS tile transpose) ----------------
__global__ __launch_bounds__(256) void k_transp(const ushort_t* __restrict__ SHB,
                                                ushort_t* __restrict__ SHBT) {
    int it = blockIdx.x, jt = blockIdx.y, zc = blockIdx.z;
    __shared__ ushort_t t[64][72];
    int tid = threadIdx.x;
#pragma unroll
    for (int g = tid; g < 512; g += 256) {
        int jj = g >> 3, cg = g & 7;
        uint4 v = *reinterpret_cast<const uint4*>(
            &SHB[((size_t)zc * LL + jt * 64 + jj) * LL + it * 64 + cg * 8]);
        *reinterpret_cast<uint4*>(&t[jj][cg * 8]) = v;
    }
    __syncthreads();
#pragma unroll
    for (int g = tid; g < 512; g += 256) {
        int ii = g >> 3, cg = g & 7;
        ushort_t tmp[8];
#pragma unroll
        for (int u = 0; u < 8; ++u) tmp[u] = t[cg * 8 + u][ii];
        *reinterpret_cast<uint4*>(
            &SHBT[((size_t)zc * LL + it * 64 + ii) * LL + jt * 64 + cg * 8]) =
            *reinterpret_cast<uint4*>(tmp);
    }
}

// ---------------- K5: fused g1/g2 main GEMMs via MFMA (unified form) ----------------
// which=0: g1[i,a] = sum_j Qh[c,i,j]  M [c,j,a] : A = SHB  rows i cols j
// which=1: g2[i,a] = sum_j Qh[c,j,i]  M2[c,j,a] : A = SHBT rows i cols j
// B = M*T [a][j] in both cases; D[i][a] direct.
__global__ __launch_bounds__(256, 4) void k_g12(const ushort_t* __restrict__ SHB,
        const ushort_t* __restrict__ SHBT,
        const ushort_t* __restrict__ MPT, const ushort_t* __restrict__ MMT,
        const ushort_t* __restrict__ MP2T, const ushort_t* __restrict__ MM2T,
        float* __restrict__ PG) {
    int it = blockIdx.x, jc = blockIdx.y;
    int which = blockIdx.z >> 4;
    int z = (blockIdx.z >> 3) & 1, c = blockIdx.z & 7;
    const ushort_t* Amat = which ? SHBT : SHB;
    const ushort_t* TP = which ? MP2T : MPT;
    const ushort_t* TM = which ? MM2T : MMT;
    __shared__ ushort_t sSH[4096], sM[4096];
    int tid = threadIdx.x;
    int w = tid >> 6, lm = tid & 15, lg = (tid & 63) >> 4;
    f32x4 acc[4];
#pragma unroll
    for (int nf = 0; nf < 4; ++nf) acc[nf] = {0.f,0.f,0.f,0.f};
    size_t shbase = ((size_t)(z * HH + c) * LL + it * 64) * LL;
    size_t mbase  = ((size_t)(z * HH + c) * DD) * LL;
    for (int js = 0; js < 4; ++js) {
        int j0 = jc * 256 + js * 64;
        bool dg = (j0 == it * 64);
        bool useP = which == 0 ? (j0 < it * 64) : (j0 > it * 64);
        __syncthreads();
        stage64(sSH, Amat + shbase + j0, LL, tid);
        stage64(sM, (dg ? TP : (useP ? TP : TM)) + mbase + j0, LL, tid);
        __syncthreads();
        for (int pass = 0; pass < (dg ? 2 : 1); ++pass) {
            if (pass == 1) {
                __syncthreads();
                stage64(sM, TM + mbase + j0, LL, tid);
                __syncthreads();
            }
#pragma unroll
            for (int ks = 0; ks < 2; ++ks) {
                int kc = ks * 32 + lg * 8;
                int jb = j0 + kc;
                bf16x8 af = frag(sSH, w * 16 + lm, kc);
                if (dg) {
                    int i = it * 64 + w * 16 + lm;
                    int cnt = (which == 0) ? iclamp(i - jb, 0, 8) : iclamp(i + 1 - jb, 0, 8);
                    af = maskfrag(af, cnt, (pass == 0) == (which == 0));
                }
#pragma unroll
                for (int nf = 0; nf < 4; ++nf)
                    acc[nf] = MFMA(af, frag(sM, nf * 16 + lm, kc), acc[nf]);
            }
        }
    }
    int slot = which * 16 + c * 2 + jc;
#pragma unroll
    for (int nf = 0; nf < 4; ++nf)
#pragma unroll
        for (int r = 0; r < 4; ++r) {
            int i = it * 64 + w * 16 + lg * 4 + r;
            int a = nf * 16 + lm;
            PG[((size_t)(slot * BB + z) * LL + i) * DD + a] = acc[nf][r];
        }
}

// ---------------- K5b: band corrections (exact term - what main added) ----------------
__global__ __launch_bounds__(256) void k_corr12(const float* __restrict__ SH,
        const ushort_t* __restrict__ M1Nb, const ushort_t* __restrict__ M2Nb,
        const ushort_t* __restrict__ MPNb, const ushort_t* __restrict__ MMNb,
        const ushort_t* __restrict__ MP2Nb, const ushort_t* __restrict__ MM2Nb,
        const float* __restrict__ dp, float* __restrict__ PG) {
    int bid = blockIdx.x;
    int which = bid >> 9; bid &= 511;
    int w = bid * 4 + (threadIdx.x >> 6);
    int lane = threadIdx.x & 63;
    int ch = w & 1, i = (w >> 1) & 511, z = w >> 10;
    const ushort_t* Mx = which ? M2Nb : M1Nb;
    const ushort_t* MPb = which ? MP2Nb : MPNb;
    const ushort_t* MMb = which ? MM2Nb : MMNb;
    float acc = 0.f;
    for (int cc = 0; cc < 4; ++cc) {
        int c = ch * 4 + cc;
#pragma unroll
        for (int d = -3; d <= 3; ++d) {
            int j = which ? i + d : i - d;
            if (j < 0 || j >= LL) continue;
            float qh = which ? SH[(((size_t)z * HH + c) * LL + j) * LL + i]
                             : SH[(((size_t)z * HH + c) * LL + i) * LL + j];
            float qh_b = b2f(f2b(qh));
            int idx = d < 0 ? d + 9 : d;
            float e = 0.f;
            if (idx != 0) {
#pragma unroll
                for (int k = 0; k < 4; ++k)
                    e += dp[(idx - 1) * 4 + k] *
                         b2f(Mx[((((size_t)z * KK + k) * HH + c) * LL + j) * DD + lane]);
            }
            const ushort_t* mb = (d > 0) ? MPb : MMb;
            float mn = b2f(mb[(((size_t)z * HH + c) * LL + j) * DD + lane]);
            acc += qh * e - qh_b * mn;
        }
    }
    int slot = 32 + which * 2 + ch;
    PG[(((size_t)slot * BB + z) * LL + i) * DD + lane] = acc;
}

// ---------------- K7: q_next = x + sum(NSLOT slots) + gg ----------------
__global__ __launch_bounds__(256) void k_update(const float* __restrict__ x, const float* __restrict__ PG,
                         const float* __restrict__ QG, const float* __restrict__ gp,
                         float* __restrict__ outq) {
    __shared__ __align__(16) float gpS[64][68];
    int tid = threadIdx.x;
#pragma unroll
    for (int idx = tid; idx < 4096; idx += 256) gpS[idx >> 6][idx & 63] = gp[idx];
    __syncthreads();
    int row = blockIdx.x * 4 + (tid >> 6);
    int a = tid & 63;
    float acc = x[row * DD + a];
    float qgv = QG[row * GG + a];
#pragma unroll 8
    for (int g = 0; g < 64; ++g) acc += __shfl(qgv, g, 64) * gpS[g][a];
#pragma unroll 6
    for (int s = 0; s < NSLOT; ++s) acc += PG[((size_t)s * BB * LL + row) * DD + a];
    outq[row * DD + a] = acc;
}

extern "C" void kernel_launch(void* const* d_in, const int* in_sizes, int n_in,
                              void* d_out, int out_size, void* d_ws, size_t ws_size,
                              hipStream_t stream) {
    const float* x    = (const float*)d_in[0];
    const int*   mask = (const int*)d_in[1];
    const float* dp   = (const float*)d_in[2];
    const float* T    = (const float*)d_in[3];
    const float* gp   = (const float*)d_in[4];
    float* out = (float*)d_out;

    float* p = (float*)d_ws;
    float* Qz = p;                        p += 65536;
    ushort_t* QzB = (ushort_t*)p;         p += 32768;
    ushort_t* M1Nb = (ushort_t*)p;        p += 1048576;
    ushort_t* M2Nb = (ushort_t*)p;        p += 1048576;
    ushort_t* MPNb  = (ushort_t*)p;       p += 262144;
    ushort_t* MMNb  = (ushort_t*)p;       p += 262144;
    ushort_t* MP2Nb = (ushort_t*)p;       p += 262144;
    ushort_t* MM2Nb = (ushort_t*)p;       p += 262144;
    ushort_t* MPT   = (ushort_t*)p;       p += 262144;
    ushort_t* MMT   = (ushort_t*)p;       p += 262144;
    ushort_t* MP2T  = (ushort_t*)p;       p += 262144;
    ushort_t* MM2T  = (ushort_t*)p;       p += 262144;
    float* BAND = p;                      p += 65536;
    float* SH   = p;                      p += 4194304;
    ushort_t* SHB  = (ushort_t*)p;        p += 2097152;
    ushort_t* SHBT = (ushort_t*)p;        p += 2097152;
    float* QG   = p;                      p += 65536;
    float* PG   = p;                      p += (size_t)NSLOT * 65536;
    float* QZ1  = p;                      p += 65536;
    // total ~61 MB (same footprint class as the passing R2/R3)

    const float* qsrc = x;
    for (int iter = 0; iter < 2; ++iter) {
        float* qdst = (iter == 0) ? QZ1 : out;
        hipLaunchKernelGGL(k_softmax_qz, dim3(256), dim3(256), 0, stream, qsrc, Qz, QzB);
        hipLaunchKernelGGL(k_compute_M, dim3(8, 8, 8), dim3(256), 0, stream, Qz, T, M1Nb, M2Nb);
        hipLaunchKernelGGL(k_collapse, dim3(8, 16), dim3(256), 0, stream, M1Nb, M2Nb, dp,
                           MPNb, MMNb, MP2Nb, MM2Nb, MPT, MMT, MP2T, MM2T);
        hipLaunchKernelGGL(k_aux2, dim3(2304), dim3(256), 0, stream, Qz, M1Nb, dp, gp, mask, BAND, QG);
        hipLaunchKernelGGL(k_sh, dim3(8, 8, 16), dim3(256), 0, stream, QzB, MPNb, MMNb, BAND, mask, SH);
        hipLaunchKernelGGL(k_softmax_sh, dim3(2048), dim3(256), 0, stream, SH, SHB);
        hipLaunchKernelGGL(k_transp, dim3(8, 8, 16), dim3(256), 0, stream, SHB, SHBT);
        hipLaunchKernelGGL(k_g12, dim3(8, 2, 32), dim3(256), 0, stream, SHB, SHBT,
                           MPT, MMT, MP2T, MM2T, PG);
        hipLaunchKernelGGL(k_corr12, dim3(1024), dim3(256), 0, stream, SH, M1Nb, M2Nb,
                           MPNb, MMNb, MP2Nb, MM2Nb, dp, PG);
        hipLaunchKernelGGL(k_update, dim3(256), dim3(256), 0, stream, x, PG, QG, gp, qdst);
        qsrc = qdst;
    }
}

// Round 7
// 150.100 us; speedup vs baseline: 2.6146x; 1.2999x over previous
//
#include <hip/hip_runtime.h>

#define BB 2
#define LL 512
#define DD 64
#define HH 8
#define GG 64
#define KK 4
#define NEGV -1e9f
#define NSLOT 36

typedef unsigned short ushort_t;
typedef __attribute__((ext_vector_type(8))) short bf16x8;
typedef __attribute__((ext_vector_type(4))) float f32x4;
#define MFMA(a, b, c) __builtin_amdgcn_mfma_f32_16x16x32_bf16(a, b, c, 0, 0, 0)

__device__ __forceinline__ ushort_t f2b(float f) {
    unsigned int u = __float_as_uint(f);
    return (ushort_t)((u + 0x7FFFu + ((u >> 16) & 1u)) >> 16);
}
__device__ __forceinline__ float b2f(ushort_t s) {
    return __uint_as_float(((unsigned int)s) << 16);
}

// stage a 64x64 bf16 tile (row-major, rowstride elems) into LDS with granule-XOR swizzle
__device__ __forceinline__ void stage64(ushort_t* dst, const ushort_t* src,
                                        int rowstride, int tid) {
#pragma unroll
    for (int g = tid; g < 512; g += 256) {
        int row = g >> 3, colg = g & 7;
        uint4 v = *reinterpret_cast<const uint4*>(&src[row * rowstride + (colg << 3)]);
        *reinterpret_cast<uint4*>(&dst[(row << 6) + ((colg ^ (row & 7)) << 3)]) = v;
    }
}
// read an 8-elem fragment (col multiple of 8) from swizzled LDS tile
__device__ __forceinline__ bf16x8 frag(const ushort_t* s, int row, int col) {
    return *reinterpret_cast<const bf16x8*>(&s[(row << 6) + ((((col >> 3) ^ (row & 7))) << 3)]);
}
__device__ __forceinline__ bf16x8 maskfrag(bf16x8 v, int cnt, bool keep_prefix) {
    bf16x8 r;
#pragma unroll
    for (int u = 0; u < 8; ++u) {
        bool keep = keep_prefix ? (u < cnt) : (u >= cnt);
        r[u] = keep ? v[u] : (short)0;
    }
    return r;
}
__device__ __forceinline__ int iclamp(int v, int lo, int hi) {
    return v < lo ? lo : (v > hi ? hi : v);
}

// ---------------- K0 (once): T -> bf16 MFMA operand tiles ----------------
// TB1[(k*8+c)][a][b] = T[k,a,b,c];  TB2[(k*8+c)][a][b] = T[k,b,a,c]
__global__ __launch_bounds__(256) void k_prepT(const float* __restrict__ T,
                                               ushort_t* __restrict__ TB1,
                                               ushort_t* __restrict__ TB2) {
    int k = blockIdx.x >> 3, c = blockIdx.x & 7;   // 32 blocks
    int tid = threadIdx.x;
    for (int g = tid; g < 512; g += 256) {
        int a = g >> 3, b0 = (g & 7) * 8;
        ushort_t o1[8], o2[8];
#pragma unroll
        for (int u = 0; u < 8; ++u) {
            o1[u] = f2b(T[(((k * 64 + a) * 64) + b0 + u) * 8 + c]);
            o2[u] = f2b(T[(((k * 64 + b0 + u) * 64) + a) * 8 + c]);
        }
        size_t base = ((size_t)(k * 8 + c) * 64 + a) * 64 + b0;
        *reinterpret_cast<uint4*>(&TB1[base]) = *reinterpret_cast<uint4*>(o1);
        *reinterpret_cast<uint4*>(&TB2[base]) = *reinterpret_cast<uint4*>(o2);
    }
}

// ---------------- K1: Q_z = softmax(q_z) over d=64; fp32 + bf16 outputs ----------------
__global__ __launch_bounds__(256) void k_softmax_qz(const float* __restrict__ src,
                                                    float* __restrict__ Qz,
                                                    ushort_t* __restrict__ QzB) {
    int row = blockIdx.x * 4 + (threadIdx.x >> 6);
    int lane = threadIdx.x & 63;
    float v = src[row * DD + lane];
    float m = v;
#pragma unroll
    for (int o = 32; o > 0; o >>= 1) m = fmaxf(m, __shfl_xor(m, o, 64));
    float e = __expf(v - m);
    float s = e;
#pragma unroll
    for (int o = 32; o > 0; o >>= 1) s += __shfl_xor(s, o, 64);
    float r = e / s;
    Qz[row * DD + lane] = r;
    QzB[row * DD + lane] = f2b(r);
}

// ---------------- K2: M1/M2 via MFMA.  M1[j,a] = sum_b Qz[j,b] TB1[a,b] ----------------
__global__ __launch_bounds__(256) void k_compute_M(const ushort_t* __restrict__ QzB,
        const ushort_t* __restrict__ TB1, const ushort_t* __restrict__ TB2,
        ushort_t* __restrict__ M1Nb, ushort_t* __restrict__ M2Nb) {
    int jt = blockIdx.x, c = blockIdx.y;
    int z = blockIdx.z >> 2, k = blockIdx.z & 3;
    __shared__ ushort_t sQ[4096], sB1[4096], sB2[4096];
    int tid = threadIdx.x;
    stage64(sQ, QzB + (size_t)(z * LL + jt * 64) * DD, DD, tid);
    size_t tb = (size_t)(k * 8 + c) * 4096;
    stage64(sB1, TB1 + tb, 64, tid);
    stage64(sB2, TB2 + tb, 64, tid);
    __syncthreads();
    int w = tid >> 6, lm = tid & 15, lg = (tid & 63) >> 4;
    f32x4 a1[4], a2[4];
#pragma unroll
    for (int nf = 0; nf < 4; ++nf) { a1[nf] = {0.f,0.f,0.f,0.f}; a2[nf] = {0.f,0.f,0.f,0.f}; }
#pragma unroll
    for (int ks = 0; ks < 2; ++ks) {
        int kc = ks * 32 + lg * 8;
        bf16x8 af = frag(sQ, w * 16 + lm, kc);
#pragma unroll
        for (int nf = 0; nf < 4; ++nf) {
            a1[nf] = MFMA(af, frag(sB1, nf * 16 + lm, kc), a1[nf]);
            a2[nf] = MFMA(af, frag(sB2, nf * 16 + lm, kc), a2[nf]);
        }
    }
    size_t base = (((size_t)z * KK + k) * HH + c) * LL;
#pragma unroll
    for (int nf = 0; nf < 4; ++nf)
#pragma unroll
        for (int r = 0; r < 4; ++r) {
            int j = jt * 64 + w * 16 + lg * 4 + r;
            int a = nf * 16 + lm;
            M1Nb[(base + j) * DD + a] = f2b(a1[nf][r]);
            M2Nb[(base + j) * DD + a] = f2b(a2[nf][r]);
        }
}

// ---------------- K3: muxed {collapse 128 blk} {band 2048 blk} {qg 256 blk} ----------------
__global__ __launch_bounds__(256, 4) void k_collaux(const float* __restrict__ Qz,
        const ushort_t* __restrict__ M1Nb, const ushort_t* __restrict__ M2Nb,
        const float* __restrict__ dp, const float* __restrict__ gp, const int* __restrict__ mask,
        ushort_t* __restrict__ MPNb, ushort_t* __restrict__ MMNb,
        ushort_t* __restrict__ MP2Nb, ushort_t* __restrict__ MM2Nb,
        ushort_t* __restrict__ MPT, ushort_t* __restrict__ MMT,
        ushort_t* __restrict__ MP2T, ushort_t* __restrict__ MM2T,
        float* __restrict__ BAND, float* __restrict__ QG) {
    __shared__ __align__(16) ushort_t sT[4 * 64 * 65];   // 33.3 KB (overlaid by qg's gpS)
    int tid = threadIdx.x;
    int b = blockIdx.x;
    if (b < 128) {
        // ---- collapse ----
        int jt = b & 7, zc = b >> 3;
        int z = zc >> 3, c = zc & 7;
        ushort_t* sP1 = sT;
        ushort_t* sM1 = sT + 64 * 65;
        ushort_t* sP2 = sT + 2 * 64 * 65;
        ushort_t* sM2 = sT + 3 * 64 * 65;
        float w4[4], w5[4];
#pragma unroll
        for (int k = 0; k < 4; ++k) { w4[k] = dp[12 + k]; w5[k] = dp[16 + k]; }
        size_t b0 = (((size_t)z * KK * HH + c) * LL + jt * 64) * DD;
        const size_t kstr = (size_t)HH * LL * DD;
        for (int g = tid; g < 512; g += 256) {
            int j = g >> 3, a0 = (g & 7) * 8;
            size_t o = b0 + (size_t)j * DD + a0;
            float p1[8] = {}, q1[8] = {}, p2[8] = {}, q2[8] = {};
#pragma unroll
            for (int k = 0; k < 4; ++k) {
                uint4 v1 = *reinterpret_cast<const uint4*>(&M1Nb[o + k * kstr]);
                uint4 v2 = *reinterpret_cast<const uint4*>(&M2Nb[o + k * kstr]);
                const ushort_t* s1 = reinterpret_cast<const ushort_t*>(&v1);
                const ushort_t* s2 = reinterpret_cast<const ushort_t*>(&v2);
#pragma unroll
                for (int u = 0; u < 8; ++u) {
                    float f1 = b2f(s1[u]), f2v = b2f(s2[u]);
                    p1[u] += w4[k] * f1; q1[u] += w5[k] * f1;
                    p2[u] += w4[k] * f2v; q2[u] += w5[k] * f2v;
                }
            }
            ushort_t t1[8], t2[8], t3[8], t4[8];
#pragma unroll
            for (int u = 0; u < 8; ++u) {
                t1[u] = f2b(p1[u]); t2[u] = f2b(q1[u]); t3[u] = f2b(p2[u]); t4[u] = f2b(q2[u]);
                sP1[(a0 + u) * 65 + j] = t1[u]; sM1[(a0 + u) * 65 + j] = t2[u];
                sP2[(a0 + u) * 65 + j] = t3[u]; sM2[(a0 + u) * 65 + j] = t4[u];
            }
            size_t on = ((size_t)zc * LL + jt * 64 + j) * DD + a0;
            *reinterpret_cast<uint4*>(&MPNb[on])  = *reinterpret_cast<uint4*>(t1);
            *reinterpret_cast<uint4*>(&MMNb[on])  = *reinterpret_cast<uint4*>(t2);
            *reinterpret_cast<uint4*>(&MP2Nb[on]) = *reinterpret_cast<uint4*>(t3);
            *reinterpret_cast<uint4*>(&MM2Nb[on]) = *reinterpret_cast<uint4*>(t4);
        }
        __syncthreads();
        for (int g = tid; g < 512; g += 256) {
            int a = g >> 3, j0 = (g & 7) * 8;
            ushort_t o1[8], o2[8], o3[8], o4[8];
#pragma unroll
            for (int u = 0; u < 8; ++u) {
                o1[u] = sP1[a * 65 + j0 + u]; o2[u] = sM1[a * 65 + j0 + u];
                o3[u] = sP2[a * 65 + j0 + u]; o4[u] = sM2[a * 65 + j0 + u];
            }
            size_t ot = ((size_t)zc * DD + a) * LL + jt * 64 + j0;
            *reinterpret_cast<uint4*>(&MPT[ot])  = *reinterpret_cast<uint4*>(o1);
            *reinterpret_cast<uint4*>(&MMT[ot])  = *reinterpret_cast<uint4*>(o2);
            *reinterpret_cast<uint4*>(&MP2T[ot]) = *reinterpret_cast<uint4*>(o3);
            *reinterpret_cast<uint4*>(&MM2T[ot]) = *reinterpret_cast<uint4*>(o4);
        }
    } else if (b < 2176) {
        // ---- band: BAND[z,c,j,d+3] = sum_a Qz[j+d,a]*(sum_k wt[tdx(d)][k]*M1[k,c,j,a]) ----
        int w = (b - 128) * 4 + (tid >> 6);
        int lane = tid & 63;
        int j = w & 511, c = (w >> 9) & 7, z = w >> 12;
        float m[4];
#pragma unroll
        for (int k = 0; k < 4; ++k)
            m[k] = b2f(M1Nb[((((size_t)z * KK + k) * HH + c) * LL + j) * DD + lane]);
        float out = 0.f;
#pragma unroll
        for (int d = -3; d <= 3; ++d) {
            int i = j + d;
            if (i < 0 || i >= LL) continue;
            int idx = d < 0 ? d + 9 : d;
            float t = 0.f;
            if (idx != 0) {
#pragma unroll
                for (int k = 0; k < 4; ++k) t += dp[(idx - 1) * 4 + k] * m[k];
            }
            float s = Qz[(z * LL + i) * DD + lane] * t;
#pragma unroll
            for (int o = 32; o > 0; o >>= 1) s += __shfl_xor(s, o, 64);
            if (lane == d + 3) out = s;
        }
        if (lane < 7) BAND[(size_t)w * 8 + lane] = out;
    } else {
        // ---- qg ----
        float* gpS = reinterpret_cast<float*>(sT);   // [g][68]
#pragma unroll
        for (int idx = tid; idx < 4096; idx += 256) gpS[(idx >> 6) * 68 + (idx & 63)] = gp[idx];
        __syncthreads();
        int row = (b - 2176) * 4 + (tid >> 6);
        int g = tid & 63;
        float qv = Qz[row * DD + g];
        float s = 0.f;
#pragma unroll 8
        for (int a = 0; a < 64; ++a) s += __shfl(qv, a, 64) * gpS[g * 68 + a];
        if (mask[row] == 0) s = NEGV;
        float m = s;
#pragma unroll
        for (int o = 32; o > 0; o >>= 1) m = fmaxf(m, __shfl_xor(m, o, 64));
        float e = __expf(s - m);
        float sum = e;
#pragma unroll
        for (int o = 32; o > 0; o >>= 1) sum += __shfl_xor(sum, o, 64);
        QG[row * GG + g] = e / sum;
    }
}

// ---------------- K4: s_h via MFMA + band overwrite + mask ----------------
__global__ __launch_bounds__(256, 4) void k_sh(const ushort_t* __restrict__ QzB,
        const ushort_t* __restrict__ MPNb, const ushort_t* __restrict__ MMNb,
        const float* __restrict__ BAND, const int* __restrict__ mask,
        float* __restrict__ SH) {
    int jt = blockIdx.x, it = blockIdx.y;
    int z = blockIdx.z >> 3, c = blockIdx.z & 7;
    __shared__ ushort_t sA[4096], sB[4096];
    int tid = threadIdx.x;
    stage64(sA, QzB + ((size_t)(z * LL + it * 64)) * DD, DD, tid);
    bool diag = (it == jt);
    size_t bbase = ((size_t)(z * HH + c) * LL + jt * 64) * DD;
    const ushort_t* B0 = diag ? MPNb : (it > jt ? MPNb : MMNb);
    stage64(sB, B0 + bbase, DD, tid);
    __syncthreads();
    int w = tid >> 6, lm = tid & 15, lg = (tid & 63) >> 4;
    f32x4 accP[4], accM[4];
#pragma unroll
    for (int nf = 0; nf < 4; ++nf) { accP[nf] = {0.f,0.f,0.f,0.f}; accM[nf] = {0.f,0.f,0.f,0.f}; }
#pragma unroll
    for (int ks = 0; ks < 2; ++ks) {
        int kc = ks * 32 + lg * 8;
        bf16x8 af = frag(sA, w * 16 + lm, kc);
#pragma unroll
        for (int nf = 0; nf < 4; ++nf)
            accP[nf] = MFMA(af, frag(sB, nf * 16 + lm, kc), accP[nf]);
    }
    if (diag) {
        __syncthreads();
        stage64(sB, MMNb + bbase, DD, tid);
        __syncthreads();
#pragma unroll
        for (int ks = 0; ks < 2; ++ks) {
            int kc = ks * 32 + lg * 8;
            bf16x8 af = frag(sA, w * 16 + lm, kc);
#pragma unroll
            for (int nf = 0; nf < 4; ++nf)
                accM[nf] = MFMA(af, frag(sB, nf * 16 + lm, kc), accM[nf]);
        }
    }
    int mi[4];
#pragma unroll
    for (int r = 0; r < 4; ++r) mi[r] = mask[z * LL + it * 64 + w * 16 + lg * 4 + r];
#pragma unroll
    for (int nf = 0; nf < 4; ++nf) {
        int j = jt * 64 + nf * 16 + lm;
        int mjv = mask[z * LL + j];
#pragma unroll
        for (int r = 0; r < 4; ++r) {
            int i = it * 64 + w * 16 + lg * 4 + r;
            float v = (diag && i <= j) ? accM[nf][r] : accP[nf][r];
            int d = i - j;
            if (d >= -3 && d <= 3)
                v = BAND[((size_t)((z * HH + c) * LL + j)) * 8 + (d + 3)];
            if (!(mi[r] && mjv)) v = NEGV;
            SH[((size_t)(z * HH + c) * LL + i) * LL + j] = v;
        }
    }
}

// ---------------- K5: Q_h softmax over j; bf16 output only ----------------
__global__ __launch_bounds__(256) void k_softmax_sh(const float* __restrict__ SH,
                                                    ushort_t* __restrict__ SHB) {
    int row = blockIdx.x * 4 + (threadIdx.x >> 6);
    int lane = threadIdx.x & 63;
    float v[8];
    float m = -1e30f;
#pragma unroll
    for (int r = 0; r < 8; ++r) { v[r] = SH[(size_t)row * LL + r * 64 + lane]; m = fmaxf(m, v[r]); }
#pragma unroll
    for (int o = 32; o > 0; o >>= 1) m = fmaxf(m, __shfl_xor(m, o, 64));
    float s = 0.f;
#pragma unroll
    for (int r = 0; r < 8; ++r) { v[r] = __expf(v[r] - m); s += v[r]; }
#pragma unroll
    for (int o = 32; o > 0; o >>= 1) s += __shfl_xor(s, o, 64);
    float inv = 1.f / s;
#pragma unroll
    for (int r = 0; r < 8; ++r)
        SHB[(size_t)row * LL + r * 64 + lane] = f2b(v[r] * inv);
}

// ---------------- K6: SHBT[zc][i][j] = SHB[zc][j][i] ----------------
__global__ __launch_bounds__(256) void k_transp(const ushort_t* __restrict__ SHB,
                                                ushort_t* __restrict__ SHBT) {
    int it = blockIdx.x, jt = blockIdx.y, zc = blockIdx.z;
    __shared__ ushort_t t[64][72];
    int tid = threadIdx.x;
#pragma unroll
    for (int g = tid; g < 512; g += 256) {
        int jj = g >> 3, cg = g & 7;
        uint4 v = *reinterpret_cast<const uint4*>(
            &SHB[((size_t)zc * LL + jt * 64 + jj) * LL + it * 64 + cg * 8]);
        *reinterpret_cast<uint4*>(&t[jj][cg * 8]) = v;
    }
    __syncthreads();
#pragma unroll
    for (int g = tid; g < 512; g += 256) {
        int ii = g >> 3, cg = g & 7;
        ushort_t tmp[8];
#pragma unroll
        for (int u = 0; u < 8; ++u) tmp[u] = t[cg * 8 + u][ii];
        *reinterpret_cast<uint4*>(
            &SHBT[((size_t)zc * LL + it * 64 + ii) * LL + jt * 64 + cg * 8]) =
            *reinterpret_cast<uint4*>(tmp);
    }
}

// ---------------- K7: muxed {g12 main GEMMs (512 blk)} {corr12 (1024 blk)} ----------------
__global__ __launch_bounds__(256, 4) void k_g12corr(const ushort_t* __restrict__ SHB,
        const ushort_t* __restrict__ SHBT,
        const ushort_t* __restrict__ MPT, const ushort_t* __restrict__ MMT,
        const ushort_t* __restrict__ MP2T, const ushort_t* __restrict__ MM2T,
        const ushort_t* __restrict__ M1Nb, const ushort_t* __restrict__ M2Nb,
        const ushort_t* __restrict__ MPNb, const ushort_t* __restrict__ MMNb,
        const ushort_t* __restrict__ MP2Nb, const ushort_t* __restrict__ MM2Nb,
        const float* __restrict__ dp, float* __restrict__ PG) {
    __shared__ ushort_t sSH[4096], sM[4096];
    int tid = threadIdx.x;
    int b = blockIdx.x;
    if (b < 512) {
        // ---- g12: which=0: g1[i,a]=sum_j Qh[i,j] M[j,a]; which=1: uses SHBT ----
        int it = b & 7, jc = (b >> 3) & 1, zcw = b >> 4;
        int which = zcw >> 4;
        int z = (zcw >> 3) & 1, c = zcw & 7;
        const ushort_t* Amat = which ? SHBT : SHB;
        const ushort_t* TP = which ? MP2T : MPT;
        const ushort_t* TM = which ? MM2T : MMT;
        int w = tid >> 6, lm = tid & 15, lg = (tid & 63) >> 4;
        f32x4 acc[4];
#pragma unroll
        for (int nf = 0; nf < 4; ++nf) acc[nf] = {0.f,0.f,0.f,0.f};
        size_t shbase = ((size_t)(z * HH + c) * LL + it * 64) * LL;
        size_t mbase  = ((size_t)(z * HH + c) * DD) * LL;
        for (int js = 0; js < 4; ++js) {
            int j0 = jc * 256 + js * 64;
            bool dg = (j0 == it * 64);
            bool useP = which == 0 ? (j0 < it * 64) : (j0 > it * 64);
            __syncthreads();
            stage64(sSH, Amat + shbase + j0, LL, tid);
            stage64(sM, (dg ? TP : (useP ? TP : TM)) + mbase + j0, LL, tid);
            __syncthreads();
            for (int pass = 0; pass < (dg ? 2 : 1); ++pass) {
                if (pass == 1) {
                    __syncthreads();
                    stage64(sM, TM + mbase + j0, LL, tid);
                    __syncthreads();
                }
#pragma unroll
                for (int ks = 0; ks < 2; ++ks) {
                    int kc = ks * 32 + lg * 8;
                    int jb = j0 + kc;
                    bf16x8 af = frag(sSH, w * 16 + lm, kc);
                    if (dg) {
                        int i = it * 64 + w * 16 + lm;
                        int cnt = (which == 0) ? iclamp(i - jb, 0, 8) : iclamp(i + 1 - jb, 0, 8);
                        af = maskfrag(af, cnt, (pass == 0) == (which == 0));
                    }
#pragma unroll
                    for (int nf = 0; nf < 4; ++nf)
                        acc[nf] = MFMA(af, frag(sM, nf * 16 + lm, kc), acc[nf]);
                }
            }
        }
        int slot = which * 16 + c * 2 + jc;
#pragma unroll
        for (int nf = 0; nf < 4; ++nf)
#pragma unroll
            for (int r = 0; r < 4; ++r) {
                int i = it * 64 + w * 16 + lg * 4 + r;
                int a = nf * 16 + lm;
                PG[((size_t)(slot * BB + z) * LL + i) * DD + a] = acc[nf][r];
            }
    } else {
        // ---- corr12: band corrections, qh from bf16 SHB ----
        int bid = b - 512;
        int which = bid >> 9; bid &= 511;
        int w = bid * 4 + (tid >> 6);
        int lane = tid & 63;
        int ch = w & 1, i = (w >> 1) & 511, z = w >> 10;
        const ushort_t* Mx = which ? M2Nb : M1Nb;
        const ushort_t* MPb = which ? MP2Nb : MPNb;
        const ushort_t* MMb = which ? MM2Nb : MMNb;
        float acc = 0.f;
        for (int cc = 0; cc < 4; ++cc) {
            int c = ch * 4 + cc;
#pragma unroll
            for (int d = -3; d <= 3; ++d) {
                int j = which ? i + d : i - d;
                if (j < 0 || j >= LL) continue;
                float qh = which ? b2f(SHB[(((size_t)z * HH + c) * LL + j) * LL + i])
                                 : b2f(SHB[(((size_t)z * HH + c) * LL + i) * LL + j]);
                int idx = d < 0 ? d + 9 : d;
                float e = 0.f;
                if (idx != 0) {
#pragma unroll
                    for (int k = 0; k < 4; ++k)
                        e += dp[(idx - 1) * 4 + k] *
                             b2f(Mx[((((size_t)z * KK + k) * HH + c) * LL + j) * DD + lane]);
                }
                const ushort_t* mb = (d > 0) ? MPb : MMb;
                float mn = b2f(mb[(((size_t)z * HH + c) * LL + j) * DD + lane]);
                acc += qh * (e - mn);
            }
        }
        int slot = 32 + which * 2 + ch;
        PG[(((size_t)slot * BB + z) * LL + i) * DD + lane] = acc;
    }
}

// ---------------- K8: q_next = x + sum(NSLOT slots) + gg ----------------
__global__ __launch_bounds__(256) void k_update(const float* __restrict__ x, const float* __restrict__ PG,
                         const float* __restrict__ QG, const float* __restrict__ gp,
                         float* __restrict__ outq) {
    __shared__ __align__(16) float gpS[64][68];
    int tid = threadIdx.x;
#pragma unroll
    for (int idx = tid; idx < 4096; idx += 256) gpS[idx >> 6][idx & 63] = gp[idx];
    __syncthreads();
    int row = blockIdx.x * 4 + (tid >> 6);
    int a = tid & 63;
    float acc = x[row * DD + a];
    float qgv = QG[row * GG + a];
#pragma unroll 8
    for (int g = 0; g < 64; ++g) acc += __shfl(qgv, g, 64) * gpS[g][a];
#pragma unroll 6
    for (int s = 0; s < NSLOT; ++s) acc += PG[((size_t)s * BB * LL + row) * DD + a];
    outq[row * DD + a] = acc;
}

extern "C" void kernel_launch(void* const* d_in, const int* in_sizes, int n_in,
                              void* d_out, int out_size, void* d_ws, size_t ws_size,
                              hipStream_t stream) {
    const float* x    = (const float*)d_in[0];
    const int*   mask = (const int*)d_in[1];
    const float* dp   = (const float*)d_in[2];
    const float* T    = (const float*)d_in[3];
    const float* gp   = (const float*)d_in[4];
    float* out = (float*)d_out;

    float* p = (float*)d_ws;
    float* Qz = p;                        p += 65536;
    ushort_t* QzB = (ushort_t*)p;         p += 32768;
    ushort_t* TB1 = (ushort_t*)p;         p += 65536;
    ushort_t* TB2 = (ushort_t*)p;         p += 65536;
    ushort_t* M1Nb = (ushort_t*)p;        p += 1048576;
    ushort_t* M2Nb = (ushort_t*)p;        p += 1048576;
    ushort_t* MPNb  = (ushort_t*)p;       p += 262144;
    ushort_t* MMNb  = (ushort_t*)p;       p += 262144;
    ushort_t* MP2Nb = (ushort_t*)p;       p += 262144;
    ushort_t* MM2Nb = (ushort_t*)p;       p += 262144;
    ushort_t* MPT   = (ushort_t*)p;       p += 262144;
    ushort_t* MMT   = (ushort_t*)p;       p += 262144;
    ushort_t* MP2T  = (ushort_t*)p;       p += 262144;
    ushort_t* MM2T  = (ushort_t*)p;       p += 262144;
    float* BAND = p;                      p += 65536;
    float* SH   = p;                      p += 4194304;
    ushort_t* SHB  = (ushort_t*)p;        p += 2097152;
    ushort_t* SHBT = (ushort_t*)p;        p += 2097152;
    float* QG   = p;                      p += 65536;
    float* PG   = p;                      p += (size_t)NSLOT * 65536;
    float* QZ1  = p;                      p += 65536;
    // total ~61.5 MB (ws is ~256 MB per fill counter)

    hipLaunchKernelGGL(k_prepT, dim3(32), dim3(256), 0, stream, T, TB1, TB2);

    const float* qsrc = x;
    for (int iter = 0; iter < 2; ++iter) {
        float* qdst = (iter == 0) ? QZ1 : out;
        hipLaunchKernelGGL(k_softmax_qz, dim3(256), dim3(256), 0, stream, qsrc, Qz, QzB);
        hipLaunchKernelGGL(k_compute_M, dim3(8, 8, 8), dim3(256), 0, stream, QzB, TB1, TB2, M1Nb, M2Nb);
        hipLaunchKernelGGL(k_collaux, dim3(2432), dim3(256), 0, stream, Qz, M1Nb, M2Nb, dp, gp, mask,
                           MPNb, MMNb, MP2Nb, MM2Nb, MPT, MMT, MP2T, MM2T, BAND, QG);
        hipLaunchKernelGGL(k_sh, dim3(8, 8, 16), dim3(256), 0, stream, QzB, MPNb, MMNb, BAND, mask, SH);
        hipLaunchKernelGGL(k_softmax_sh, dim3(2048), dim3(256), 0, stream, SH, SHB);
        hipLaunchKernelGGL(k_transp, dim3(8, 8, 16), dim3(256), 0, stream, SHB, SHBT);
        hipLaunchKernelGGL(k_g12corr, dim3(1536), dim3(256), 0, stream, SHB, SHBT,
                           MPT, MMT, MP2T, MM2T, M1Nb, M2Nb,
                           MPNb, MMNb, MP2Nb, MM2Nb, dp, PG);
        hipLaunchKernelGGL(k_update, dim3(256), dim3(256), 0, stream, x, PG, QG, gp, qdst);
        qsrc = qdst;
    }
}